// Round 12
// baseline (560.192 us; speedup 1.0000x reference)
//
#include <hip/hip_runtime.h>

typedef unsigned short u16;
typedef __attribute__((ext_vector_type(8))) short bf16x8;   // 8 x bf16 (4 VGPRs)
typedef __attribute__((ext_vector_type(4))) float f32x4;

#define NLEV 5
#define CCH 256
#define KTOT 2304            // 9 taps * 256 ci
#define P_TOT 8525           // sum HW
#define PP_TOT 9165          // sum (H+2)*(W+2)
#define PLS (PP_TOT*64)      // activation plane stride (u16), 4 planes of 64 ci
#define HSTR 11776           // halo LDS plane stride (u16) = 23 slabs * 512

__constant__ int   c_HW[NLEV]     = {6400, 1600, 400, 100, 25};
__constant__ int   c_W[NLEV]      = {80, 40, 20, 10, 5};    // H == W (square)
__constant__ int   c_off[NLEV]    = {0, 6400, 8000, 8400, 8500};
__constant__ int   c_poff[NLEV]   = {0, 6724, 8488, 8972, 9116};
__constant__ int   c_tls[NLEV+1]  = {0, 50, 65, 71, 73, 74};  // 16x8 tile starts
__constant__ int   c_ntx[NLEV]    = {5, 3, 2, 1, 1};          // tiles across
__constant__ float c_stridef[NLEV]= {8.f, 16.f, 32.f, 64.f, 128.f};

__device__ __forceinline__ u16 f2bf(float f){
  union { float f; unsigned u; } v; v.f = f;
  unsigned r = v.u + 0x7fffu + ((v.u >> 16) & 1u);   // RNE
  return (u16)(r >> 16);
}

// ---------------------------------------------------------------------------
// Register-A halo implicit-GEMM conv 3x3. NO global_load_lds anywhere:
//  - A (weights): packed in FRAGMENT ORDER (lane ln's 16B at base+ln*16,
//    cc-major stages s=t) and loaded straight to VGPRs, 4 coalesced
//    global_load_dwordx4 per wave per stage, triple-buffered (distance-2).
//    Compiler pipelines these freely (no LDS-DMA aliasing hazards).
//  - B (activations): 18x10 halo per 64-ci plane in LDS, 2-plane dbuf,
//    staged via uint4 register loads + ds_write_b128 (loads at tap==7,
//    writes after the cc-boundary barrier). 4 barriers total.
// Tile: block = 16x8 px x 128 co, wave = 32 co x 128 px, full K (36 stages,
// t = cc*9 + tap), 32 MFMA/stage/wave. LDS 47.2 KB -> 2 blocks/CU.
// MODE 0: towers, grid (74, 2 mtiles, 2 br); GN stats fused in epilogue.
// MODE 1: heads,  grid (74, 1, 2): br0 score (m<80), br1 pred+iou (m<5).
// ---------------------------------------------------------------------------
template<int MODE>
__global__ __launch_bounds__(256, 2) void gemm_conv(
    const u16* __restrict__ Xc, const u16* __restrict__ Xb,
    const u16* __restrict__ Wc, const u16* __restrict__ Wb,
    const float* __restrict__ bc, const float* __restrict__ bb,
    float* __restrict__ Yc, float* __restrict__ Yb,
    float* __restrict__ stats,
    const float* __restrict__ predb, const float* __restrict__ ioub,
    const float* __restrict__ scales, float* __restrict__ out)
{
  __shared__ u16 hB[2*HSTR];        // 47104 B: halo plane dbuf (slot = cc&1)
  __shared__ float sstat[16][2];

  const int ptile = blockIdx.x;
  const int mtile = (MODE == 0) ? blockIdx.y : 0;
  const int br = blockIdx.z;
  int lv = 0;
  #pragma unroll
  for (int i = 1; i < NLEV; i++) if (ptile >= c_tls[i]) lv = i;
  const int tidx = ptile - c_tls[lv];
  const int ntx = c_ntx[lv];
  const int ty0 = (tidx / ntx) * 8, tx0 = (tidx - (tidx / ntx) * ntx) * 16;
  const int W = c_W[lv], wrow2 = W + 2;

  const int tid = threadIdx.x, wv = tid >> 6, ln = tid & 63;
  const int quad = ln >> 4, l15 = ln & 15;

  const u16* __restrict__ X  = br ? Xb : Xc;   // planar activations
  const u16* __restrict__ WA = br ? Wb : Wc;   // fragment-packed weights

  // A fragment pointers: frag (mt,sub) of stage s lives at
  // base + ((s*8 + (wv*2+mt))*2 + sub)*512 + ln*8   (u16 units)
  const u16* ap[2][2];
  const u16* abase = WA + (size_t)((MODE == 0) ? mtile*294912 : 0);
  #pragma unroll
  for (int mt = 0; mt < 2; mt++)
    #pragma unroll
    for (int sub = 0; sub < 2; sub++)
      ap[mt][sub] = abase + (((wv*2 + mt)*2 + sub)*512) + ln*8;

  // Halo per-lane source pointers: slab j = wv+4i (j>22 -> idempotent dup).
  const u16* hptr[6]; int hslab[6];
  #pragma unroll
  for (int i = 0; i < 6; i++) {
    int j = wv + 4*i;
    if (j > 22) j -= 4;
    hslab[i] = j;
    const int item = j*64 + ln;
    int hp = item >> 3; if (hp >= 180) hp -= 180;
    const int g = item & 7;
    const int hy = hp / 18, hx = hp - hy*18;
    const int prow = c_poff[lv] + (ty0 + hy)*wrow2 + tx0 + hx;
    hptr[i] = X + (size_t)prow*64 + ((g ^ (hp & 7)) << 3);
  }

  uint4 hreg[6];
  auto hload = [&](int plane) {
    #pragma unroll
    for (int i = 0; i < 6; i++)
      hreg[i] = *(const uint4*)(hptr[i] + (size_t)plane * PLS);
  };
  auto hwrite = [&](int plane) {
    u16* dst = &hB[(plane & 1) * HSTR];
    #pragma unroll
    for (int i = 0; i < 6; i++)
      *(uint4*)&dst[hslab[i]*512 + ln*8] = hreg[i];
  };

  bf16x8 aB[3][2][2];
  auto aload = [&](int s, int b) {
    #pragma unroll
    for (int mt = 0; mt < 2; mt++)
      #pragma unroll
      for (int sub = 0; sub < 2; sub++)
        aB[b][mt][sub] = *(const bf16x8*)(ap[mt][sub] + (size_t)s*8192);
  };

  f32x4 acc[2][8];
  #pragma unroll
  for (int i = 0; i < 2; i++)
    #pragma unroll
    for (int j = 0; j < 8; j++) acc[i][j] = (f32x4){0.f, 0.f, 0.f, 0.f};

  if (MODE == 0 && tid < 32) sstat[tid >> 1][tid & 1] = 0.f;

  // ---- prologue: halo planes 0,1 + A stages 0,1; one barrier ----
  hload(0); hwrite(0);
  hload(1); hwrite(1);
  aload(0, 0);
  aload(1, 1);
  __syncthreads();

  // ---- K-loop (fully unrolled; t = cc*9 + tap; A stage index == t) ----
  #pragma unroll
  for (int t = 0; t < 36; t++) {
    const int cc = t / 9, tap = t - cc*9;
    if (tap == 0 && cc > 0) {          // t = 9, 18, 27
      __syncthreads();                 // prior slot reads done; writes visible
      if (cc < 3) hwrite(cc + 1);      // plane loaded 2 stages ago
    }
    if (tap == 7 && cc < 2) hload(cc + 2);
    if (t < 34) aload(t + 2, (t + 2) % 3);
    const u16* hpl = &hB[(cc & 1) * HSTR];
    const int dh = tap / 3, dw = tap - dh*3;
    #pragma unroll
    for (int sub = 0; sub < 2; sub++) {
      const int q = sub*4 + quad;
      bf16x8 bf[8];
      #pragma unroll
      for (int nt = 0; nt < 8; nt++) {
        const int hp = (nt + dh)*18 + l15 + dw;
        bf[nt] = *(const bf16x8*)&hpl[hp*64 + ((q ^ (hp & 7)) << 3)];
      }
      #pragma unroll
      for (int mt = 0; mt < 2; mt++)
        #pragma unroll
        for (int nt = 0; nt < 8; nt++)
          acc[mt][nt] = __builtin_amdgcn_mfma_f32_16x16x32_bf16(
              aB[t % 3][mt][sub], bf[nt], acc[mt][nt], 0, 0, 0);
    }
  }

  const int gx = tx0 + l15;
  if (MODE == 0) {
    const float* __restrict__ bias = br ? bb : bc;
    float* __restrict__ Y = br ? Yb : Yc;
    #pragma unroll
    for (int mt = 0; mt < 2; mt++) {
      const int mloc = wv*32 + mt*16 + quad*4;
      const int mrow = mtile*128 + mloc;
      const f32x4 bv = *(const f32x4*)&bias[mrow];
      float s = 0.f, sq = 0.f;
      #pragma unroll
      for (int nt = 0; nt < 8; nt++) {
        const int gy = ty0 + nt;
        f32x4 v = acc[mt][nt] + bv;
        if (gy < W && gx < W) {
          const size_t n = (size_t)(c_off[lv] + gy*W + gx);
          *(f32x4*)&Y[n*CCH + mrow] = v;
          #pragma unroll
          for (int r = 0; r < 4; r++) { s += v[r]; sq += v[r]*v[r]; }
        }
      }
      #pragma unroll
      for (int o = 1; o < 16; o <<= 1) { s += __shfl_xor(s, o); sq += __shfl_xor(sq, o); }
      if (l15 == 0) {
        const int g = mloc >> 3;               // local 8-ch GN group 0..15
        atomicAdd(&sstat[g][0], s);
        atomicAdd(&sstat[g][1], sq);
      }
    }
    __syncthreads();
    if (tid < 32) {
      const int g = tid >> 1, c = tid & 1;
      atomicAdd(&stats[((br*NLEV + lv)*32 + mtile*16 + g)*2 + c], sstat[g][c]);
    }
  } else {
    const float scl = scales[lv];
    const float stf = c_stridef[lv];
    #pragma unroll
    for (int mt = 0; mt < 2; mt++) {
      const int mr0 = wv*32 + mt*16 + quad*4;
      if (mr0 >= 85) continue;
      #pragma unroll
      for (int nt = 0; nt < 8; nt++) {
        const int gy = ty0 + nt;
        if (gy >= W || gx >= W) continue;
        const size_t n = (size_t)(c_off[lv] + gy*W + gx);
        const f32x4 v = acc[mt][nt];
        #pragma unroll
        for (int r = 0; r < 4; r++) {
          const int m = mr0 + r;
          if (br == 0) {
            if (m < 80) out[n*85 + m] = v[r] + bc[m];          // logits
          } else {
            if (m < 4) {
              const float t = (v[r] + predb[m]) * scl;         // Scale module
              out[n*85 + 80 + m] = fmaxf(t, 0.f) * stf;        // relu * stride
            } else if (m == 4) {
              out[n*85 + 84] = v[r] + ioub[0];                 // iou
            }
          }
        }
      }
    }
  }
}

// GN finalize + affine + ReLU + bf16 cast into PLANAR padded layout.
// Y already includes conv bias.
__global__ __launch_bounds__(256) void gn_relu(
    const float* __restrict__ Yc, const float* __restrict__ Yb,
    const float* __restrict__ stats,
    const float* __restrict__ gwc, const float* __restrict__ gbc,
    const float* __restrict__ gwb, const float* __restrict__ gbb,
    u16* __restrict__ Xc, u16* __restrict__ Xb)
{
  const int t = blockIdx.x * 256 + threadIdx.x;
  if (t >= 2 * P_TOT * 32) return;
  const int br = t / (P_TOT * 32);
  const int r  = t - br * (P_TOT * 32);
  const int pg = r >> 5;
  const int c0 = (r & 31) << 3;
  int lv = 0;
  #pragma unroll
  for (int i = 1; i < NLEV; i++) if (pg >= c_off[i]) lv = i;
  const int pl = pg - c_off[lv];
  const int Wl = c_W[lv];
  const int g = c0 >> 3;
  const float* st = &stats[(((size_t)br*NLEV + lv)*32 + g)*2];
  const float cnt = 8.f * (float)c_HW[lv];
  const float mean = st[0] / cnt;
  const float var  = st[1] / cnt - mean*mean;
  const float rstd = rsqrtf(var + 1e-5f);
  const float* Y  = br ? Yb : Yc;
  const float* gw = br ? gwb : gwc;
  const float* gb = br ? gbb : gbc;
  u16* X = br ? Xb : Xc;
  const float* y = &Y[(size_t)pg*CCH + c0];
  const int h = pl / Wl, wi = pl - h*Wl;
  const size_t pidx = (size_t)(c_poff[lv] + (h+1)*(Wl+2) + (wi+1));
  union { u16 u[8]; uint4 v; } pk;
  #pragma unroll
  for (int i = 0; i < 8; i++) {
    const float v = (y[i] - mean)*rstd*gw[c0+i] + gb[c0+i];
    pk.u[i] = f2bf(fmaxf(v, 0.f));
  }
  *(uint4*)&X[(size_t)(c0 >> 6)*PLS + pidx*64 + (c0 & 63)] = pk.v;
}

// fp32 NCHW feats -> bf16 planar padded
__global__ __launch_bounds__(256) void feat2bf(
    const float* __restrict__ p3, const float* __restrict__ p4,
    const float* __restrict__ p5, const float* __restrict__ p6,
    const float* __restrict__ p7, u16* __restrict__ X)
{
  const int t = blockIdx.x * 256 + threadIdx.x;
  if (t >= P_TOT * 32) return;
  const int pg = t >> 5, c0 = (t & 31) << 3;
  int lv = 0;
  #pragma unroll
  for (int i = 1; i < NLEV; i++) if (pg >= c_off[i]) lv = i;
  const int pl = pg - c_off[lv];
  const float* src = lv==0 ? p3 : lv==1 ? p4 : lv==2 ? p5 : lv==3 ? p6 : p7;
  const int HW = c_HW[lv], Wl = c_W[lv];
  const int h = pl / Wl, wi = pl - h*Wl;
  const size_t pidx = (size_t)(c_poff[lv] + (h+1)*(Wl+2) + (wi+1));
  union { u16 u[8]; uint4 v; } pk;
  #pragma unroll
  for (int i = 0; i < 8; i++)
    pk.u[i] = f2bf(src[(size_t)(c0+i)*HW + pl]);
  *(uint4*)&X[(size_t)(c0 >> 6)*PLS + pidx*64 + (c0 & 63)] = pk.v;
}

// tower weights [l][co][ci][9] fp32 -> FRAGMENT-ORDER pack, cc-major stages:
// s' = (ci>>6)*9 + tap (0..35); kl = ci&63; sub=kl>>5; quad=(kl>>3)&3; j=kl&7
// ln = quad*16 + (co&15); mtl = (co>>4)&7; comtile = co>>7
// dst = l*589824 + comtile*294912 + ((s'*8 + mtl)*2 + sub)*512 + ln*8 + j
__global__ __launch_bounds__(256) void wconv(
    const float* __restrict__ cw, const float* __restrict__ bw,
    u16* __restrict__ Wc, u16* __restrict__ Wb)
{
  const size_t N = (size_t)4*256*KTOT;
  const size_t t = (size_t)blockIdx.x * 256 + threadIdx.x;
  if (t >= 2*N) return;
  const float* src = (t < N) ? cw : bw;
  u16* dst = (t < N) ? Wc : Wb;
  const size_t i = (t < N) ? t : t - N;
  const size_t lc = i / KTOT;
  const int kk = (int)(i - lc*KTOT);
  const int l = (int)(lc >> 8), co = (int)(lc & 255);
  const int tap = kk >> 8, ci = kk & 255;
  const int s = (ci >> 6)*9 + tap;
  const int kl = ci & 63;
  const int sub = kl >> 5, quad = (kl >> 3) & 3, j = kl & 7;
  const int ln = quad*16 + (co & 15);
  const int mtl = (co >> 4) & 7, comtile = co >> 7;
  const size_t d = (size_t)l*589824 + (size_t)comtile*294912 +
      ((size_t)((s*8 + mtl)*2 + sub))*512 + ln*8 + j;
  dst[d] = f2bf(src[(lc*256 + ci)*9 + tap]);
}

// head weights -> fragment-order pack, 128 rows (cls 80 / box 4+1, padded)
__global__ __launch_bounds__(256) void hconv(
    const float* __restrict__ sw, const float* __restrict__ pw,
    const float* __restrict__ iw, u16* __restrict__ Whc, u16* __restrict__ Whb)
{
  const int N = 128 * KTOT;
  const int t = blockIdx.x * 256 + threadIdx.x;
  if (t >= 2*N) return;
  const int i = (t < N) ? t : t - N;
  const int co = i / KTOT, kk = i - co*KTOT;
  const int tap = kk >> 8, ci = kk & 255;
  const int s = (ci >> 6)*9 + tap;
  const int kl = ci & 63;
  const int sub = kl >> 5, quad = (kl >> 3) & 3, j = kl & 7;
  const int ln = quad*16 + (co & 15);
  const int mtl = co >> 4;
  const size_t d = ((size_t)((s*8 + mtl)*2 + sub))*512 + ln*8 + j;
  float v = 0.f;
  if (t < N) {
    if (co < 80) v = sw[(co*256 + ci)*9 + tap];
    Whc[d] = f2bf(v);
  } else {
    if (co < 4)       v = pw[(co*256 + ci)*9 + tap];
    else if (co == 4) v = iw[ci*9 + tap];
    Whb[d] = f2bf(v);
  }
}

extern "C" void kernel_launch(void* const* d_in, const int* in_sizes, int n_in,
                              void* d_out, int out_size, void* d_ws, size_t ws_size,
                              hipStream_t stream)
{
  const float* p3      = (const float*)d_in[0];
  const float* p4      = (const float*)d_in[1];
  const float* p5      = (const float*)d_in[2];
  const float* p6      = (const float*)d_in[3];
  const float* p7      = (const float*)d_in[4];
  const float* cls_w   = (const float*)d_in[5];
  const float* cls_b   = (const float*)d_in[6];
  const float* cls_gw  = (const float*)d_in[7];
  const float* cls_gb  = (const float*)d_in[8];
  const float* box_w   = (const float*)d_in[9];
  const float* box_b   = (const float*)d_in[10];
  const float* box_gw  = (const float*)d_in[11];
  const float* box_gb  = (const float*)d_in[12];
  const float* score_w = (const float*)d_in[13];
  const float* score_b = (const float*)d_in[14];
  const float* pred_w  = (const float*)d_in[15];
  const float* pred_b  = (const float*)d_in[16];
  const float* iou_w   = (const float*)d_in[17];
  const float* iou_b   = (const float*)d_in[18];
  const float* scales  = (const float*)d_in[19];
  float* out = (float*)d_out;

  char* w = (char*)d_ws;
  size_t o = 0;
  auto alloc = [&](size_t b) { void* p = w + o; o += (b + 255) & ~(size_t)255; return p; };
  // X buffers + stats first: zeroed by ONE memset (all 256B multiples)
  u16*   XF = (u16*)alloc((size_t)PP_TOT*CCH*2);   // planar [4][PP_TOT][64]
  u16*   XC = (u16*)alloc((size_t)PP_TOT*CCH*2);
  u16*   XB = (u16*)alloc((size_t)PP_TOT*CCH*2);
  float* ST = (float*)alloc((size_t)4*2*NLEV*32*2*4);   // [layer][br][lv][32][2]
  u16*  WRC = (u16*)alloc((size_t)4*256*KTOT*2);
  u16*  WRB = (u16*)alloc((size_t)4*256*KTOT*2);
  u16*  WHC = (u16*)alloc((size_t)128*KTOT*2);
  u16*  WHB = (u16*)alloc((size_t)128*KTOT*2);
  float* YC = (float*)alloc((size_t)P_TOT*CCH*4);
  float* YB = (float*)alloc((size_t)P_TOT*CCH*4);

  // zero padded activation borders + all layers' GN stats in one shot
  hipMemsetAsync(XF, 0, (size_t)3*PP_TOT*CCH*2 + (size_t)4*2*NLEV*32*2*4, stream);

  wconv<<<dim3((unsigned)(((size_t)2*4*256*KTOT + 255)/256)), 256, 0, stream>>>(cls_w, box_w, WRC, WRB);
  hconv<<<dim3((2*128*KTOT + 255)/256), 256, 0, stream>>>(score_w, pred_w, iou_w, WHC, WHB);
  feat2bf<<<dim3((P_TOT*32 + 255)/256), 256, 0, stream>>>(p3, p4, p5, p6, p7, XF);

  const u16* xci = XF; const u16* xbi = XF;
  for (int l = 0; l < 4; l++) {
    float* STl = ST + (size_t)l*2*NLEV*32*2;
    gemm_conv<0><<<dim3(74, 2, 2), 256, 0, stream>>>(
        xci, xbi, WRC + (size_t)l*589824, WRB + (size_t)l*589824,
        cls_b + l*256, box_b + l*256, YC, YB, STl,
        nullptr, nullptr, nullptr, nullptr);
    gn_relu<<<dim3((2*P_TOT*32 + 255)/256), 256, 0, stream>>>(
        YC, YB, STl, cls_gw + l*256, cls_gb + l*256, box_gw + l*256, box_gb + l*256,
        XC, XB);
    xci = XC; xbi = XB;
  }
  gemm_conv<1><<<dim3(74, 1, 2), 256, 0, stream>>>(
      xci, xbi, WHC, WHB, score_b, nullptr, nullptr, nullptr, nullptr,
      pred_b, iou_b, scales, out);
}